// Round 7
// baseline (152.318 us; speedup 1.0000x reference)
//
#include <hip/hip_runtime.h>

typedef short s16x8 __attribute__((ext_vector_type(8)));
typedef short s16x4 __attribute__((ext_vector_type(4)));
typedef float f32x4 __attribute__((ext_vector_type(4)));
typedef float f4 __attribute__((ext_vector_type(4)));
typedef unsigned short u16x4 __attribute__((ext_vector_type(4)));

#define CEXP 14.426950408889634074f   // 10 * log2(e)

__device__ __forceinline__ unsigned short f2bf(float f) {
    union { float f; unsigned int i; } v; v.f = f;
    unsigned int x = v.i;
    return (unsigned short)((x + 0x7fffu + ((x >> 16) & 1u)) >> 16);  // RNE
}
__device__ __forceinline__ float bf2f(unsigned short u) {
    union { unsigned int i; float f; } v; v.i = ((unsigned int)u) << 16; return v.f;
}

// pack 4 fp32 -> 4 bf16 (element order preserved)
__device__ __forceinline__ s16x4 pk_bf16x4(float p0, float p1, float p2, float p3) {
#if __has_builtin(__builtin_amdgcn_cvt_pk_bf16_f32)
    typedef __bf16 bf16x2 __attribute__((ext_vector_type(2)));
    union { struct { bf16x2 a, b; } h; s16x4 s; } r;
    r.h.a = __builtin_amdgcn_cvt_pk_bf16_f32(p0, p1);
    r.h.b = __builtin_amdgcn_cvt_pk_bf16_f32(p2, p3);
    return r.s;
#else
    unsigned u0 = __float_as_uint(p0) + 0x8000u;
    unsigned u1 = __float_as_uint(p1) + 0x8000u;
    unsigned u2 = __float_as_uint(p2) + 0x8000u;
    unsigned u3 = __float_as_uint(p3) + 0x8000u;
    union { uint2 u; s16x4 s; } pb;
    pb.u.x = __builtin_amdgcn_perm(u1, u0, 0x07060302u);
    pb.u.y = __builtin_amdgcn_perm(u3, u2, 0x07060302u);
    return pb.s;
#endif
}

__device__ __forceinline__ u16x4 pk4(f4 v) {
    u16x4 r = { f2bf(v[0]), f2bf(v[1]), f2bf(v[2]), f2bf(v[3]) };
    return r;
}

// ---------------------------------------------------------------------------
// k_prep v2 (unchanged): coalesced 64x64 LDS-tile transposes.
// ---------------------------------------------------------------------------
__global__ __launch_bounds__(256) void k_prep(
    const float* __restrict__ Wqkv, const float* __restrict__ Wout,
    unsigned short* __restrict__ Wt, unsigned short* __restrict__ WoT,
    float* __restrict__ sumsqp)
{
    __shared__ float tile[64][65];
    const int blk = blockIdx.x, tid = threadIdx.x;
    if (blk >= 16) {
        sumsqp[(blk - 16) * 256 + tid] = 0.f;     // 32 blocks x 256 = 8192
        return;
    }
    const float* src;
    unsigned short* dst;
    int lds_src, k0, n0;
    if (blk < 12) {
        src = Wqkv; dst = Wt; lds_src = 384;
        k0 = (blk & 1) * 64; n0 = (blk >> 1) * 64;
    } else {
        int b = blk - 12;
        src = Wout; dst = WoT; lds_src = 128;
        k0 = (b & 1) * 64; n0 = (b >> 1) * 64;
    }
    const int c = tid & 63, r0 = tid >> 6;
#pragma unroll
    for (int i = 0; i < 16; ++i) {
        int row = i * 4 + r0;
        tile[row][c] = src[(size_t)(k0 + row) * lds_src + n0 + c];
    }
    __syncthreads();
#pragma unroll
    for (int i = 0; i < 16; ++i) {
        int n = i * 4 + r0;
        dst[(size_t)(n0 + n) * 128 + k0 + c] = f2bf(tile[c][n]);
    }
}

// ---------------------------------------------------------------------------
// k_qkv v6 (unchanged).
// ---------------------------------------------------------------------------
__global__ __launch_bounds__(256, 2) void k_qkv(
    const float* __restrict__ x, const unsigned short* __restrict__ Wt,
    unsigned short* __restrict__ Qb, unsigned short* __restrict__ Kb,
    unsigned short* __restrict__ Vt, float* __restrict__ sumsqp)
{
    __shared__ float red[4][64];
    const int tid = threadIdx.x;
    const int wl = tid >> 6, lane = tid & 63;
    const int qd = lane >> 4, nn = lane & 15;
    const int n0 = blockIdx.y * 64;            // global output col base
    const int tw0 = blockIdx.x * 64 + wl * 16; // token base for this wave

    const float* apf = x + (size_t)(tw0 + nn) * 128 + qd * 8;
    const unsigned short* bp = Wt + (size_t)(n0 + nn) * 128 + qd * 8;
    s16x8 af[4], bfr[16];
#pragma unroll
    for (int ks = 0; ks < 4; ++ks) {
        f4 a0 = *(const f4*)(apf + ks * 32);
        f4 a1 = *(const f4*)(apf + ks * 32 + 4);
        union { struct { s16x4 lo, hi; } h; s16x8 v; } u;
        u.h.lo = pk_bf16x4(a0[0], a0[1], a0[2], a0[3]);
        u.h.hi = pk_bf16x4(a1[0], a1[1], a1[2], a1[3]);
        af[ks] = u.v;
    }
#pragma unroll
    for (int nb = 0; nb < 4; ++nb)
#pragma unroll
        for (int ks = 0; ks < 4; ++ks)
            bfr[nb * 4 + ks] = *(const s16x8*)(bp + (size_t)nb * 2048 + ks * 32);

    f32x4 acc[4];
#pragma unroll
    for (int nb = 0; nb < 4; ++nb) acc[nb] = (f32x4){0.f, 0.f, 0.f, 0.f};

    const int cb = n0 >> 7;            // 0=q 1=k 2=v
    const int b = tw0 >> 12;           // batch (block-uniform: 64 | 4096)
    const int tl0 = tw0 & 4095;        // token within batch

    if (cb < 2) {
        // A = W rows (out-cols), B = x rows (tokens)
#pragma unroll
        for (int ks = 0; ks < 4; ++ks)
#pragma unroll
            for (int nb = 0; nb < 4; ++nb)
                acc[nb] = __builtin_amdgcn_mfma_f32_16x16x32_bf16(bfr[nb * 4 + ks], af[ks], acc[nb], 0, 0, 0);
        unsigned short* dst = (cb == 0) ? Qb : Kb;
        const int tok = tl0 + nn;
#pragma unroll
        for (int nb = 0; nb < 4; ++nb) {
            const int dim = (n0 & 127) + nb * 16 + qd * 4;   // 4-aligned, +r
            const int h = dim >> 5, d0 = dim & 31;
            *(u16x4*)&dst[(size_t)((b * 4 + h) * 4096 + tok) * 32 + d0] = pk4(acc[nb]);
            f32x4 ss;
#pragma unroll
            for (int r = 0; r < 4; ++r) ss[r] = acc[nb][r] * acc[nb][r];
#pragma unroll
            for (int m = 1; m < 16; m <<= 1) {
#pragma unroll
                for (int r = 0; r < 4; ++r) ss[r] += __shfl_xor(ss[r], m);
            }
            if (nn == 0)
                *(f4*)&red[wl][nb * 16 + qd * 4] = ss;   // slab partial, this wave
        }
        __syncthreads();                       // block-uniform branch: safe
        if (tid < 64) {
            float s = red[0][tid] + red[1][tid] + red[2][tid] + red[3][tid];
            const int g = (cb << 9) + (b << 7) + (n0 & 127) + tid;
            atomicAdd(&sumsqp[((blockIdx.x & 7) << 10) + g], s);
        }
    } else {
        // A = x rows (tokens), B = W rows (out-cols): D row = token = 4qd+r
#pragma unroll
        for (int ks = 0; ks < 4; ++ks)
#pragma unroll
            for (int nb = 0; nb < 4; ++nb)
                acc[nb] = __builtin_amdgcn_mfma_f32_16x16x32_bf16(af[ks], bfr[nb * 4 + ks], acc[nb], 0, 0, 0);
#pragma unroll
        for (int nb = 0; nb < 4; ++nb) {
            const int dim = (n0 & 127) + nb * 16 + nn;
            const int h = dim >> 5, d = dim & 31;
            *(u16x4*)&Vt[(size_t)((b * 4 + h) * 32 + d) * 4096 + tl0 + qd * 4] = pk4(acc[nb]);
        }
    }
}

// ---------------------------------------------------------------------------
// k_attn v14 = v13 body + schedule fix (R18: pipe totals dropped 37-45% but
// wall only -6% -> pipes SERIALIZE; per-jt CU budget LDS 1920 + MFMA 1550 +
// VALU ~900 cyc ~= 4350 cyc wall).  Two schedule-only changes, pipe totals
// invariant:
//  1. prefetch loads issued AFTER __syncthreads (barrier lowers to
//     s_waitcnt vmcnt(0) -- issuing loads right before it ate the full L2
//     latency at the barrier where no wave can progress; now the vmcnt wait
//     lands at the tail ds_write, hidden under ~2 js32 of compute).
//  2. js32 order de-phased by wl parity: odd waves run js32 {1,0} -- half
//     the CU is in QK/exp while the other half is in PV, so LDS/trans/matrix
//     pipes see overlapping demand instead of lockstep bursts.
// ---------------------------------------------------------------------------
__global__ __launch_bounds__(512, 4) void k_attn(
    const unsigned short* __restrict__ Qb, const unsigned short* __restrict__ Kb,
    const unsigned short* __restrict__ Vt, const float* __restrict__ sumsqp,
    unsigned short* __restrict__ Ogb)
{
    __shared__ char smem[32768];
    const int tid  = threadIdx.x;
    const int wv   = tid >> 6, lane = tid & 63;
    const int wl   = wv & 3, half = wv >> 2;
    const int qd   = lane >> 4, nn = lane & 15;
    const int bh   = blockIdx.x;
    const int ib   = blockIdx.y * 128 + wl * 32;
    const unsigned short* Qbh = Qb + (size_t)bh * 4096 * 32;
    const unsigned short* Kbh = Kb + (size_t)bh * 4096 * 32;
    const unsigned short* Vbh = Vt + (size_t)bh * 32 * 4096;

    // rj[d] = min(rsqrt(ssq_q),1e12) * min(rsqrt(ssq_k),1e12) * CEXP
    float rj[8];
    {
        const int gq = bh * 32 + qd * 8;
#pragma unroll
        for (int j = 0; j < 8; ++j) {
            float sq = 0.f, sk = 0.f;
#pragma unroll
            for (int c = 0; c < 8; ++c) {
                sq += sumsqp[c * 1024 + gq + j];
                sk += sumsqp[c * 1024 + 512 + gq + j];
            }
            rj[j] = fminf(__builtin_amdgcn_rsqf(sq), 1e12f)
                  * fminf(__builtin_amdgcn_rsqf(sk), 1e12f) * CEXP;
        }
    }

    s16x8 q0r = *(const s16x8*)(Qbh + (ib + nn) * 32 + qd * 8);
    s16x8 q1r = *(const s16x8*)(Qbh + (ib + 16 + nn) * 32 + qd * 8);
    s16x8 qf0, qf1;
#pragma unroll
    for (int j = 0; j < 8; ++j) {
        qf0[j] = (short)f2bf(bf2f((unsigned short)q0r[j]) * rj[j]);
        qf1[j] = (short)f2bf(bf2f((unsigned short)q1r[j]) * rj[j]);
    }

    f32x4 o00 = {0.f,0.f,0.f,0.f}, o01 = {0.f,0.f,0.f,0.f};
    f32x4 o10 = {0.f,0.f,0.f,0.f}, o11 = {0.f,0.f,0.f,0.f};
    f32x4 la  = {0.f,0.f,0.f,0.f}, lb  = {0.f,0.f,0.f,0.f};
    const f32x4 zro = {0.f,0.f,0.f,0.f};
    const s16x8 ones8 = { (short)0x3F80, (short)0x3F80, (short)0x3F80, (short)0x3F80,
                          (short)0x3F80, (short)0x3F80, (short)0x3F80, (short)0x3F80 };

    const int KB0 = half * 8192;
    const int VB0 = 16384 + half * 8192;
    const int jb0 = half * 2048;

    // K staging: wave wl fills LDS tile wl, rows nn, j-permuted
    const int jperm = ((wl >> 1) << 5) + ((nn >> 2) << 3) + ((wl & 1) << 2) + (nn & 3);
    const unsigned short* ksrc = Kbh + (size_t)(jb0 + jperm) * 32 + qd * 8;
    // V staging: wave wl -> (dhalf=wl>>1, js32=wl&1); lane: d=nn, tok=qd*8..+7
    const unsigned short* vsrc = Vbh + (size_t)((wl >> 1) * 16 + nn) * 4096
                               + jb0 + (wl & 1) * 32 + qd * 8;
    char* kdst = smem + KB0 + wl * 1024 + lane * 16;
    char* vdst = smem + VB0 + wl * 1024 + lane * 16;

    {   // preload tile 0 -> buffer 0
        uint4 gk = *(const uint4*)ksrc;
        uint4 gv = *(const uint4*)vsrc;
        ksrc += 2048; vsrc += 64;
        *(uint4*)kdst = gk;
        *(uint4*)vdst = gv;
    }

    const int swz = wl & 1;   // js32 order de-phase

    for (int jt = 0; jt < 32; ++jt) {
        __syncthreads();
        // issue tile jt+1 prefetch AFTER the barrier (jt=31: in-ws, unused)
        uint4 ngk = *(const uint4*)ksrc;
        uint4 ngv = *(const uint4*)vsrc;
        ksrc += 2048; vsrc += 64;

        const char* kcur = smem + KB0 + (jt & 1) * 4096;
        const char* vcur = smem + VB0 + (jt & 1) * 4096;
#pragma unroll
        for (int s = 0; s < 2; ++s) {
            const int js32 = s ^ swz;
            s16x8 kf0 = *(const s16x8*)(kcur + (js32 * 2 + 0) * 1024 + lane * 16);
            s16x8 kf1 = *(const s16x8*)(kcur + (js32 * 2 + 1) * 1024 + lane * 16);
            f32x4 sa0 = __builtin_amdgcn_mfma_f32_16x16x32_bf16(kf0, qf0, zro, 0, 0, 0);
            f32x4 sb0 = __builtin_amdgcn_mfma_f32_16x16x32_bf16(kf0, qf1, zro, 0, 0, 0);
            f32x4 sa1 = __builtin_amdgcn_mfma_f32_16x16x32_bf16(kf1, qf0, zro, 0, 0, 0);
            f32x4 sb1 = __builtin_amdgcn_mfma_f32_16x16x32_bf16(kf1, qf1, zro, 0, 0, 0);
            float a0 = __builtin_amdgcn_exp2f(sa0[0]);
            float a1 = __builtin_amdgcn_exp2f(sa0[1]);
            float a2 = __builtin_amdgcn_exp2f(sa0[2]);
            float a3 = __builtin_amdgcn_exp2f(sa0[3]);
            float a4 = __builtin_amdgcn_exp2f(sa1[0]);
            float a5 = __builtin_amdgcn_exp2f(sa1[1]);
            float a6 = __builtin_amdgcn_exp2f(sa1[2]);
            float a7 = __builtin_amdgcn_exp2f(sa1[3]);
            float b0 = __builtin_amdgcn_exp2f(sb0[0]);
            float b1 = __builtin_amdgcn_exp2f(sb0[1]);
            float b2 = __builtin_amdgcn_exp2f(sb0[2]);
            float b3 = __builtin_amdgcn_exp2f(sb0[3]);
            float b4 = __builtin_amdgcn_exp2f(sb1[0]);
            float b5 = __builtin_amdgcn_exp2f(sb1[1]);
            float b6 = __builtin_amdgcn_exp2f(sb1[2]);
            float b7 = __builtin_amdgcn_exp2f(sb1[3]);
            union { struct { s16x4 lo, hi; } h; s16x8 v; } ua, ub;
            ua.h.lo = pk_bf16x4(a0, a1, a2, a3);
            ua.h.hi = pk_bf16x4(a4, a5, a6, a7);
            ub.h.lo = pk_bf16x4(b0, b1, b2, b3);
            ub.h.hi = pk_bf16x4(b4, b5, b6, b7);
            s16x8 pa32 = ua.v, pb32 = ub.v;
            la = __builtin_amdgcn_mfma_f32_16x16x32_bf16(ones8, pa32, la, 0, 0, 0);
            lb = __builtin_amdgcn_mfma_f32_16x16x32_bf16(ones8, pb32, lb, 0, 0, 0);
            s16x8 va = *(const s16x8*)(vcur + js32 * 1024 + lane * 16);
            s16x8 vb = *(const s16x8*)(vcur + 2048 + js32 * 1024 + lane * 16);
            o00 = __builtin_amdgcn_mfma_f32_16x16x32_bf16(va, pa32, o00, 0, 0, 0);
            o01 = __builtin_amdgcn_mfma_f32_16x16x32_bf16(vb, pa32, o01, 0, 0, 0);
            o10 = __builtin_amdgcn_mfma_f32_16x16x32_bf16(va, pb32, o10, 0, 0, 0);
            o11 = __builtin_amdgcn_mfma_f32_16x16x32_bf16(vb, pb32, o11, 0, 0, 0);
        }
        const int nxt4k = ((jt + 1) & 1) * 4096;
        *(uint4*)(kdst + nxt4k) = ngk;   // vmcnt wait lands here, hidden by compute
        *(uint4*)(vdst + nxt4k) = ngv;
    }

    const float lpa = la[0];   // replicated over r and qd; exact row-sum for i=nn
    const float lpb = lb[0];
    __syncthreads();                           // staging LDS dead now
    float* Ob = (float*)smem;                  // [4 wl][2 it][64 lane][8] = 16KB
    float* Lb = (float*)(smem + 16384);        // [4][2][64] = 2KB
    if (half) {
        float* d0 = Ob + ((wl * 2 + 0) * 64 + lane) * 8;
        *(f4*)d0 = o00; *(f4*)(d0 + 4) = o01;
        float* d1 = Ob + ((wl * 2 + 1) * 64 + lane) * 8;
        *(f4*)d1 = o10; *(f4*)(d1 + 4) = o11;
        Lb[(wl * 2 + 0) * 64 + lane] = lpa;
        Lb[(wl * 2 + 1) * 64 + lane] = lpb;
    }
    __syncthreads();
    if (!half) {
        const int bb = bh >> 2, hh = bh & 3;
        float* s0 = Ob + ((wl * 2 + 0) * 64 + lane) * 8;
        float rla = 1.f / (lpa + Lb[(wl * 2 + 0) * 64 + lane]);
        f4 m00 = (o00 + *(const f4*)s0) * rla;
        f4 m01 = (o01 + *(const f4*)(s0 + 4)) * rla;
        float* s1 = Ob + ((wl * 2 + 1) * 64 + lane) * 8;
        float rlb = 1.f / (lpb + Lb[(wl * 2 + 1) * 64 + lane]);
        f4 m10 = (o10 + *(const f4*)s1) * rlb;
        f4 m11 = (o11 + *(const f4*)(s1 + 4)) * rlb;
        unsigned short* dst0 = Ogb + (size_t)(bb * 4096 + blockIdx.y * 128 + wl * 32 + nn) * 128
                             + hh * 32 + qd * 4;
        *(u16x4*)dst0 = pk4(m00);
        *(u16x4*)(dst0 + 16) = pk4(m01);
        unsigned short* dst1 = dst0 + (size_t)16 * 128;
        *(u16x4*)dst1 = pk4(m10);
        *(u16x4*)(dst1 + 16) = pk4(m11);
    }
}

// ---------------------------------------------------------------------------
// k_out v1 (unchanged): out = Og @ W_out + b_out.
// ---------------------------------------------------------------------------
__global__ __launch_bounds__(256, 2) void k_out(
    const unsigned short* __restrict__ Ogb, const unsigned short* __restrict__ WoT,
    const float* __restrict__ bout, float* __restrict__ out)
{
    const int tid = threadIdx.x;
    const int wl = tid >> 6, lane = tid & 63;
    const int qd = lane >> 4, nn = lane & 15;
    const int n0 = blockIdx.y * 64;            // outc base
    const int tw0 = blockIdx.x * 64 + wl * 16; // token base

    const unsigned short* ap = WoT + (size_t)(n0 + nn) * 128 + qd * 8;
    const unsigned short* bp = Ogb + (size_t)(tw0 + nn) * 128 + qd * 8;
    s16x8 bfr[4], afr[16];
#pragma unroll
    for (int ks = 0; ks < 4; ++ks) bfr[ks] = *(const s16x8*)(bp + ks * 32);
#pragma unroll
    for (int nb = 0; nb < 4; ++nb)
#pragma unroll
        for (int ks = 0; ks < 4; ++ks)
            afr[nb * 4 + ks] = *(const s16x8*)(ap + (size_t)nb * 2048 + ks * 32);

    f32x4 acc[4];
#pragma unroll
    for (int nb = 0; nb < 4; ++nb) acc[nb] = (f32x4){0.f, 0.f, 0.f, 0.f};
#pragma unroll
    for (int ks = 0; ks < 4; ++ks)
#pragma unroll
        for (int nb = 0; nb < 4; ++nb)
            acc[nb] = __builtin_amdgcn_mfma_f32_16x16x32_bf16(afr[nb * 4 + ks], bfr[ks], acc[nb], 0, 0, 0);

#pragma unroll
    for (int nb = 0; nb < 4; ++nb) {
        const int c = n0 + nb * 16 + qd * 4;
        f4 bv = *(const f4*)&bout[c];
        f4 r;
#pragma unroll
        for (int j = 0; j < 4; ++j) r[j] = acc[nb][j] + bv[j];
        *(f4*)&out[(size_t)(tw0 + nn) * 128 + c] = r;
    }
}

// ---------------------------------------------------------------------------
extern "C" void kernel_launch(void* const* d_in, const int* in_sizes, int n_in,
                              void* d_out, int out_size, void* d_ws, size_t ws_size,
                              hipStream_t stream)
{
    const float* x    = (const float*)d_in[0];
    const float* Wqkv = (const float*)d_in[1];
    const float* Wout = (const float*)d_in[2];
    const float* bout = (const float*)d_in[3];
    float* out = (float*)d_out;
    char* ws = (char*)d_ws;
    const size_t MB = 1024 * 1024;
    unsigned short* Qb  = (unsigned short*)(ws);             // 4 MB [16][4096][32] (raw q)
    unsigned short* Kb  = (unsigned short*)(ws + 4 * MB);    // 4 MB (raw k)
    unsigned short* Vt  = (unsigned short*)(ws + 8 * MB);    // 4 MB [16][32][4096]
    unsigned short* Ogb = (unsigned short*)(ws + 12 * MB);   // 4 MB [16384][128] bf16
    unsigned short* Wt  = (unsigned short*)(ws + 16 * MB);               // 96 KB
    unsigned short* WoT = (unsigned short*)(ws + 16 * MB + 112 * 1024);  // 32 KB
    float*       sumsqp = (float*)(ws + 16 * MB + 160 * 1024);           // 32 KB [8][1024]

    hipLaunchKernelGGL(k_prep, dim3(48), dim3(256), 0, stream, Wqkv, Wout, Wt, WoT, sumsqp);
    hipLaunchKernelGGL(k_qkv, dim3(256, 6), dim3(256), 0, stream, x, Wt, Qb, Kb, Vt, sumsqp);
    hipLaunchKernelGGL(k_attn, dim3(16, 32), dim3(512), 0, stream, Qb, Kb, Vt, sumsqp, Ogb);
    hipLaunchKernelGGL(k_out, dim3(256, 2), dim3(256), 0, stream, Ogb, WoT, bout, out);
}

// Round 8
// 141.199 us; speedup vs baseline: 1.0788x; 1.0788x over previous
//
#include <hip/hip_runtime.h>

typedef short s16x8 __attribute__((ext_vector_type(8)));
typedef short s16x4 __attribute__((ext_vector_type(4)));
typedef float f32x4 __attribute__((ext_vector_type(4)));
typedef float f4 __attribute__((ext_vector_type(4)));
typedef unsigned short u16x4 __attribute__((ext_vector_type(4)));

#define CEXP 14.426950408889634074f   // 10 * log2(e)

__device__ __forceinline__ unsigned short f2bf(float f) {
    union { float f; unsigned int i; } v; v.f = f;
    unsigned int x = v.i;
    return (unsigned short)((x + 0x7fffu + ((x >> 16) & 1u)) >> 16);  // RNE
}
__device__ __forceinline__ float bf2f(unsigned short u) {
    union { unsigned int i; float f; } v; v.i = ((unsigned int)u) << 16; return v.f;
}

// pack 4 fp32 -> 4 bf16 (element order preserved)
__device__ __forceinline__ s16x4 pk_bf16x4(float p0, float p1, float p2, float p3) {
#if __has_builtin(__builtin_amdgcn_cvt_pk_bf16_f32)
    typedef __bf16 bf16x2 __attribute__((ext_vector_type(2)));
    union { struct { bf16x2 a, b; } h; s16x4 s; } r;
    r.h.a = __builtin_amdgcn_cvt_pk_bf16_f32(p0, p1);
    r.h.b = __builtin_amdgcn_cvt_pk_bf16_f32(p2, p3);
    return r.s;
#else
    unsigned u0 = __float_as_uint(p0) + 0x8000u;
    unsigned u1 = __float_as_uint(p1) + 0x8000u;
    unsigned u2 = __float_as_uint(p2) + 0x8000u;
    unsigned u3 = __float_as_uint(p3) + 0x8000u;
    union { uint2 u; s16x4 s; } pb;
    pb.u.x = __builtin_amdgcn_perm(u1, u0, 0x07060302u);
    pb.u.y = __builtin_amdgcn_perm(u3, u2, 0x07060302u);
    return pb.s;
#endif
}

__device__ __forceinline__ u16x4 pk4(f4 v) {
    u16x4 r = { f2bf(v[0]), f2bf(v[1]), f2bf(v[2]), f2bf(v[3]) };
    return r;
}

// ---------------------------------------------------------------------------
// k_prep v2 (unchanged): coalesced 64x64 LDS-tile transposes.
// ---------------------------------------------------------------------------
__global__ __launch_bounds__(256) void k_prep(
    const float* __restrict__ Wqkv, const float* __restrict__ Wout,
    unsigned short* __restrict__ Wt, unsigned short* __restrict__ WoT,
    float* __restrict__ sumsqp)
{
    __shared__ float tile[64][65];
    const int blk = blockIdx.x, tid = threadIdx.x;
    if (blk >= 16) {
        sumsqp[(blk - 16) * 256 + tid] = 0.f;     // 32 blocks x 256 = 8192
        return;
    }
    const float* src;
    unsigned short* dst;
    int lds_src, k0, n0;
    if (blk < 12) {
        src = Wqkv; dst = Wt; lds_src = 384;
        k0 = (blk & 1) * 64; n0 = (blk >> 1) * 64;
    } else {
        int b = blk - 12;
        src = Wout; dst = WoT; lds_src = 128;
        k0 = (b & 1) * 64; n0 = (b >> 1) * 64;
    }
    const int c = tid & 63, r0 = tid >> 6;
#pragma unroll
    for (int i = 0; i < 16; ++i) {
        int row = i * 4 + r0;
        tile[row][c] = src[(size_t)(k0 + row) * lds_src + n0 + c];
    }
    __syncthreads();
#pragma unroll
    for (int i = 0; i < 16; ++i) {
        int n = i * 4 + r0;
        dst[(size_t)(n0 + n) * 128 + k0 + c] = f2bf(tile[c][n]);
    }
}

// ---------------------------------------------------------------------------
// k_qkv v7: 3-in-1 restructure.  R19: e2e - k_attn ~= 83us is non-attn;
// old grid (256,6) reloaded each 64-token x-slab 6x (af load + f32->bf16
// pack repeated per n0-tile) and ran 1536 blocks = 3 residency rounds.
// Now grid (256,2): each block loads af ONCE and loops categories q,k,v
// reusing it (x reads 48->16MB, pack VALU /3, 512 blocks = 2/CU, 1 round).
// Store layouts, sumsq spreading and all consumers byte-identical.
// ---------------------------------------------------------------------------
__global__ __launch_bounds__(256, 2) void k_qkv(
    const float* __restrict__ x, const unsigned short* __restrict__ Wt,
    unsigned short* __restrict__ Qb, unsigned short* __restrict__ Kb,
    unsigned short* __restrict__ Vt, float* __restrict__ sumsqp)
{
    __shared__ float red[4][64];
    const int tid = threadIdx.x;
    const int wl = tid >> 6, lane = tid & 63;
    const int qd = lane >> 4, nn = lane & 15;
    const int yb = blockIdx.y;                 // 0..1: 64-col half within category
    const int tw0 = blockIdx.x * 64 + wl * 16; // token base for this wave

    const float* apf = x + (size_t)(tw0 + nn) * 128 + qd * 8;
    s16x8 af[4];
#pragma unroll
    for (int ks = 0; ks < 4; ++ks) {
        f4 a0 = *(const f4*)(apf + ks * 32);
        f4 a1 = *(const f4*)(apf + ks * 32 + 4);
        union { struct { s16x4 lo, hi; } h; s16x8 v; } u;
        u.h.lo = pk_bf16x4(a0[0], a0[1], a0[2], a0[3]);
        u.h.hi = pk_bf16x4(a1[0], a1[1], a1[2], a1[3]);
        af[ks] = u.v;
    }

    const int b = tw0 >> 12;           // batch (block-uniform: 64 | 4096)
    const int tl0 = tw0 & 4095;        // token within batch
    const int tok = tl0 + nn;

    // ---- categories 0 (q) and 1 (k): A = W rows (out-cols), B = x rows ----
#pragma unroll
    for (int c = 0; c < 2; ++c) {
        const int n0 = c * 128 + yb * 64;
        const unsigned short* bp = Wt + (size_t)(n0 + nn) * 128 + qd * 8;
        s16x8 bfr[16];
#pragma unroll
        for (int nb = 0; nb < 4; ++nb)
#pragma unroll
            for (int ks = 0; ks < 4; ++ks)
                bfr[nb * 4 + ks] = *(const s16x8*)(bp + (size_t)nb * 2048 + ks * 32);

        f32x4 acc[4];
#pragma unroll
        for (int nb = 0; nb < 4; ++nb) acc[nb] = (f32x4){0.f, 0.f, 0.f, 0.f};
#pragma unroll
        for (int ks = 0; ks < 4; ++ks)
#pragma unroll
            for (int nb = 0; nb < 4; ++nb)
                acc[nb] = __builtin_amdgcn_mfma_f32_16x16x32_bf16(bfr[nb * 4 + ks], af[ks], acc[nb], 0, 0, 0);

        unsigned short* dst = (c == 0) ? Qb : Kb;
#pragma unroll
        for (int nb = 0; nb < 4; ++nb) {
            const int dim = yb * 64 + nb * 16 + qd * 4;      // 4-aligned, +r
            const int h = dim >> 5, d0 = dim & 31;
            *(u16x4*)&dst[(size_t)((b * 4 + h) * 4096 + tok) * 32 + d0] = pk4(acc[nb]);
            f32x4 ss;
#pragma unroll
            for (int r = 0; r < 4; ++r) ss[r] = acc[nb][r] * acc[nb][r];
#pragma unroll
            for (int m = 1; m < 16; m <<= 1) {
#pragma unroll
                for (int r = 0; r < 4; ++r) ss[r] += __shfl_xor(ss[r], m);
            }
            if (nn == 0)
                *(f4*)&red[wl][nb * 16 + qd * 4] = ss;       // slab partial
        }
        __syncthreads();                   // block-uniform: safe
        if (tid < 64) {
            float s = red[0][tid] + red[1][tid] + red[2][tid] + red[3][tid];
            const int g = (c << 9) + (b << 7) + yb * 64 + tid;
            atomicAdd(&sumsqp[((blockIdx.x & 7) << 10) + g], s);
        }
        __syncthreads();                   // red reused by next category
    }

    // ---- category 2 (v): A = x rows (tokens), B = W rows: D row = token ----
    {
        const int n0 = 256 + yb * 64;
        const unsigned short* bp = Wt + (size_t)(n0 + nn) * 128 + qd * 8;
        s16x8 bfr[16];
#pragma unroll
        for (int nb = 0; nb < 4; ++nb)
#pragma unroll
            for (int ks = 0; ks < 4; ++ks)
                bfr[nb * 4 + ks] = *(const s16x8*)(bp + (size_t)nb * 2048 + ks * 32);

        f32x4 acc[4];
#pragma unroll
        for (int nb = 0; nb < 4; ++nb) acc[nb] = (f32x4){0.f, 0.f, 0.f, 0.f};
#pragma unroll
        for (int ks = 0; ks < 4; ++ks)
#pragma unroll
            for (int nb = 0; nb < 4; ++nb)
                acc[nb] = __builtin_amdgcn_mfma_f32_16x16x32_bf16(af[ks], bfr[nb * 4 + ks], acc[nb], 0, 0, 0);
#pragma unroll
        for (int nb = 0; nb < 4; ++nb) {
            const int dim = yb * 64 + nb * 16 + nn;
            const int h = dim >> 5, d = dim & 31;
            *(u16x4*)&Vt[(size_t)((b * 4 + h) * 32 + d) * 4096 + tl0 + qd * 4] = pk4(acc[nb]);
        }
    }
}

// ---------------------------------------------------------------------------
// k_attn v13 (exact revert of v14's regression: prefetch-after-barrier +
// de-phase lost 9us, 58.0->67.2; v13 = 58.0us best).  K=32-fused PV/l-sum,
// j-permuted K staging, conflict-free lane*16 LDS reads (conflicts 98K).
// ---------------------------------------------------------------------------
__global__ __launch_bounds__(512, 4) void k_attn(
    const unsigned short* __restrict__ Qb, const unsigned short* __restrict__ Kb,
    const unsigned short* __restrict__ Vt, const float* __restrict__ sumsqp,
    unsigned short* __restrict__ Ogb)
{
    __shared__ char smem[32768];
    const int tid  = threadIdx.x;
    const int wv   = tid >> 6, lane = tid & 63;
    const int wl   = wv & 3, half = wv >> 2;
    const int qd   = lane >> 4, nn = lane & 15;
    const int bh   = blockIdx.x;
    const int ib   = blockIdx.y * 128 + wl * 32;
    const unsigned short* Qbh = Qb + (size_t)bh * 4096 * 32;
    const unsigned short* Kbh = Kb + (size_t)bh * 4096 * 32;
    const unsigned short* Vbh = Vt + (size_t)bh * 32 * 4096;

    // rj[d] = min(rsqrt(ssq_q),1e12) * min(rsqrt(ssq_k),1e12) * CEXP
    float rj[8];
    {
        const int gq = bh * 32 + qd * 8;
#pragma unroll
        for (int j = 0; j < 8; ++j) {
            float sq = 0.f, sk = 0.f;
#pragma unroll
            for (int c = 0; c < 8; ++c) {
                sq += sumsqp[c * 1024 + gq + j];
                sk += sumsqp[c * 1024 + 512 + gq + j];
            }
            rj[j] = fminf(__builtin_amdgcn_rsqf(sq), 1e12f)
                  * fminf(__builtin_amdgcn_rsqf(sk), 1e12f) * CEXP;
        }
    }

    s16x8 q0r = *(const s16x8*)(Qbh + (ib + nn) * 32 + qd * 8);
    s16x8 q1r = *(const s16x8*)(Qbh + (ib + 16 + nn) * 32 + qd * 8);
    s16x8 qf0, qf1;
#pragma unroll
    for (int j = 0; j < 8; ++j) {
        qf0[j] = (short)f2bf(bf2f((unsigned short)q0r[j]) * rj[j]);
        qf1[j] = (short)f2bf(bf2f((unsigned short)q1r[j]) * rj[j]);
    }

    f32x4 o00 = {0.f,0.f,0.f,0.f}, o01 = {0.f,0.f,0.f,0.f};
    f32x4 o10 = {0.f,0.f,0.f,0.f}, o11 = {0.f,0.f,0.f,0.f};
    f32x4 la  = {0.f,0.f,0.f,0.f}, lb  = {0.f,0.f,0.f,0.f};
    const f32x4 zro = {0.f,0.f,0.f,0.f};
    const s16x8 ones8 = { (short)0x3F80, (short)0x3F80, (short)0x3F80, (short)0x3F80,
                          (short)0x3F80, (short)0x3F80, (short)0x3F80, (short)0x3F80 };

    const int KB0 = half * 8192;
    const int VB0 = 16384 + half * 8192;
    const int jb0 = half * 2048;

    // K staging: wave wl fills LDS tile wl, rows nn, j-permuted
    const int jperm = ((wl >> 1) << 5) + ((nn >> 2) << 3) + ((wl & 1) << 2) + (nn & 3);
    const unsigned short* ksrc = Kbh + (size_t)(jb0 + jperm) * 32 + qd * 8;
    // V staging: wave wl -> (dhalf=wl>>1, js32=wl&1); lane: d=nn, tok=qd*8..+7
    const unsigned short* vsrc = Vbh + (size_t)((wl >> 1) * 16 + nn) * 4096
                               + jb0 + (wl & 1) * 32 + qd * 8;
    char* kdst = smem + KB0 + wl * 1024 + lane * 16;
    char* vdst = smem + VB0 + wl * 1024 + lane * 16;

    {   // preload tile 0 -> buffer 0
        uint4 gk = *(const uint4*)ksrc;
        uint4 gv = *(const uint4*)vsrc;
        ksrc += 2048; vsrc += 64;
        *(uint4*)kdst = gk;
        *(uint4*)vdst = gv;
    }

    for (int jt = 0; jt < 32; ++jt) {
        uint4 ngk = *(const uint4*)ksrc;     // tile jt+1 (jt=31: in-ws, unused)
        uint4 ngv = *(const uint4*)vsrc;
        ksrc += 2048; vsrc += 64;

        __syncthreads();
        const char* kcur = smem + KB0 + (jt & 1) * 4096;
        const char* vcur = smem + VB0 + (jt & 1) * 4096;
#pragma unroll
        for (int js32 = 0; js32 < 2; ++js32) {
            s16x8 kf0 = *(const s16x8*)(kcur + (js32 * 2 + 0) * 1024 + lane * 16);
            s16x8 kf1 = *(const s16x8*)(kcur + (js32 * 2 + 1) * 1024 + lane * 16);
            f32x4 sa0 = __builtin_amdgcn_mfma_f32_16x16x32_bf16(kf0, qf0, zro, 0, 0, 0);
            f32x4 sb0 = __builtin_amdgcn_mfma_f32_16x16x32_bf16(kf0, qf1, zro, 0, 0, 0);
            f32x4 sa1 = __builtin_amdgcn_mfma_f32_16x16x32_bf16(kf1, qf0, zro, 0, 0, 0);
            f32x4 sb1 = __builtin_amdgcn_mfma_f32_16x16x32_bf16(kf1, qf1, zro, 0, 0, 0);
            float a0 = __builtin_amdgcn_exp2f(sa0[0]);
            float a1 = __builtin_amdgcn_exp2f(sa0[1]);
            float a2 = __builtin_amdgcn_exp2f(sa0[2]);
            float a3 = __builtin_amdgcn_exp2f(sa0[3]);
            float a4 = __builtin_amdgcn_exp2f(sa1[0]);
            float a5 = __builtin_amdgcn_exp2f(sa1[1]);
            float a6 = __builtin_amdgcn_exp2f(sa1[2]);
            float a7 = __builtin_amdgcn_exp2f(sa1[3]);
            float b0 = __builtin_amdgcn_exp2f(sb0[0]);
            float b1 = __builtin_amdgcn_exp2f(sb0[1]);
            float b2 = __builtin_amdgcn_exp2f(sb0[2]);
            float b3 = __builtin_amdgcn_exp2f(sb0[3]);
            float b4 = __builtin_amdgcn_exp2f(sb1[0]);
            float b5 = __builtin_amdgcn_exp2f(sb1[1]);
            float b6 = __builtin_amdgcn_exp2f(sb1[2]);
            float b7 = __builtin_amdgcn_exp2f(sb1[3]);
            union { struct { s16x4 lo, hi; } h; s16x8 v; } ua, ub;
            ua.h.lo = pk_bf16x4(a0, a1, a2, a3);
            ua.h.hi = pk_bf16x4(a4, a5, a6, a7);
            ub.h.lo = pk_bf16x4(b0, b1, b2, b3);
            ub.h.hi = pk_bf16x4(b4, b5, b6, b7);
            s16x8 pa32 = ua.v, pb32 = ub.v;
            la = __builtin_amdgcn_mfma_f32_16x16x32_bf16(ones8, pa32, la, 0, 0, 0);
            lb = __builtin_amdgcn_mfma_f32_16x16x32_bf16(ones8, pb32, lb, 0, 0, 0);
            s16x8 va = *(const s16x8*)(vcur + js32 * 1024 + lane * 16);
            s16x8 vb = *(const s16x8*)(vcur + 2048 + js32 * 1024 + lane * 16);
            o00 = __builtin_amdgcn_mfma_f32_16x16x32_bf16(va, pa32, o00, 0, 0, 0);
            o01 = __builtin_amdgcn_mfma_f32_16x16x32_bf16(vb, pa32, o01, 0, 0, 0);
            o10 = __builtin_amdgcn_mfma_f32_16x16x32_bf16(va, pb32, o10, 0, 0, 0);
            o11 = __builtin_amdgcn_mfma_f32_16x16x32_bf16(vb, pb32, o11, 0, 0, 0);
        }
        const int nxt4k = ((jt + 1) & 1) * 4096;
        *(uint4*)(kdst + nxt4k) = ngk;
        *(uint4*)(vdst + nxt4k) = ngv;
    }

    const float lpa = la[0];   // replicated over r and qd; exact row-sum for i=nn
    const float lpb = lb[0];
    __syncthreads();                           // staging LDS dead now
    float* Ob = (float*)smem;                  // [4 wl][2 it][64 lane][8] = 16KB
    float* Lb = (float*)(smem + 16384);        // [4][2][64] = 2KB
    if (half) {
        float* d0 = Ob + ((wl * 2 + 0) * 64 + lane) * 8;
        *(f4*)d0 = o00; *(f4*)(d0 + 4) = o01;
        float* d1 = Ob + ((wl * 2 + 1) * 64 + lane) * 8;
        *(f4*)d1 = o10; *(f4*)(d1 + 4) = o11;
        Lb[(wl * 2 + 0) * 64 + lane] = lpa;
        Lb[(wl * 2 + 1) * 64 + lane] = lpb;
    }
    __syncthreads();
    if (!half) {
        const int bb = bh >> 2, hh = bh & 3;
        float* s0 = Ob + ((wl * 2 + 0) * 64 + lane) * 8;
        float rla = 1.f / (lpa + Lb[(wl * 2 + 0) * 64 + lane]);
        f4 m00 = (o00 + *(const f4*)s0) * rla;
        f4 m01 = (o01 + *(const f4*)(s0 + 4)) * rla;
        float* s1 = Ob + ((wl * 2 + 1) * 64 + lane) * 8;
        float rlb = 1.f / (lpb + Lb[(wl * 2 + 1) * 64 + lane]);
        f4 m10 = (o10 + *(const f4*)s1) * rlb;
        f4 m11 = (o11 + *(const f4*)(s1 + 4)) * rlb;
        unsigned short* dst0 = Ogb + (size_t)(bb * 4096 + blockIdx.y * 128 + wl * 32 + nn) * 128
                             + hh * 32 + qd * 4;
        *(u16x4*)dst0 = pk4(m00);
        *(u16x4*)(dst0 + 16) = pk4(m01);
        unsigned short* dst1 = dst0 + (size_t)16 * 128;
        *(u16x4*)dst1 = pk4(m10);
        *(u16x4*)(dst1 + 16) = pk4(m11);
    }
}

// ---------------------------------------------------------------------------
// k_out v1 (unchanged): out = Og @ W_out + b_out.
// ---------------------------------------------------------------------------
__global__ __launch_bounds__(256, 2) void k_out(
    const unsigned short* __restrict__ Ogb, const unsigned short* __restrict__ WoT,
    const float* __restrict__ bout, float* __restrict__ out)
{
    const int tid = threadIdx.x;
    const int wl = tid >> 6, lane = tid & 63;
    const int qd = lane >> 4, nn = lane & 15;
    const int n0 = blockIdx.y * 64;            // outc base
    const int tw0 = blockIdx.x * 64 + wl * 16; // token base

    const unsigned short* ap = WoT + (size_t)(n0 + nn) * 128 + qd * 8;
    const unsigned short* bp = Ogb + (size_t)(tw0 + nn) * 128 + qd * 8;
    s16x8 bfr[4], afr[16];
#pragma unroll
    for (int ks = 0; ks < 4; ++ks) bfr[ks] = *(const s16x8*)(bp + ks * 32);
#pragma unroll
    for (int nb = 0; nb < 4; ++nb)
#pragma unroll
        for (int ks = 0; ks < 4; ++ks)
            afr[nb * 4 + ks] = *(const s16x8*)(ap + (size_t)nb * 2048 + ks * 32);

    f32x4 acc[4];
#pragma unroll
    for (int nb = 0; nb < 4; ++nb) acc[nb] = (f32x4){0.f, 0.f, 0.f, 0.f};
#pragma unroll
    for (int ks = 0; ks < 4; ++ks)
#pragma unroll
        for (int nb = 0; nb < 4; ++nb)
            acc[nb] = __builtin_amdgcn_mfma_f32_16x16x32_bf16(afr[nb * 4 + ks], bfr[ks], acc[nb], 0, 0, 0);

#pragma unroll
    for (int nb = 0; nb < 4; ++nb) {
        const int c = n0 + nb * 16 + qd * 4;
        f4 bv = *(const f4*)&bout[c];
        f4 r;
#pragma unroll
        for (int j = 0; j < 4; ++j) r[j] = acc[nb][j] + bv[j];
        *(f4*)&out[(size_t)(tw0 + nn) * 128 + c] = r;
    }
}

// ---------------------------------------------------------------------------
extern "C" void kernel_launch(void* const* d_in, const int* in_sizes, int n_in,
                              void* d_out, int out_size, void* d_ws, size_t ws_size,
                              hipStream_t stream)
{
    const float* x    = (const float*)d_in[0];
    const float* Wqkv = (const float*)d_in[1];
    const float* Wout = (const float*)d_in[2];
    const float* bout = (const float*)d_in[3];
    float* out = (float*)d_out;
    char* ws = (char*)d_ws;
    const size_t MB = 1024 * 1024;
    unsigned short* Qb  = (unsigned short*)(ws);             // 4 MB [16][4096][32] (raw q)
    unsigned short* Kb  = (unsigned short*)(ws + 4 * MB);    // 4 MB (raw k)
    unsigned short* Vt  = (unsigned short*)(ws + 8 * MB);    // 4 MB [16][32][4096]
    unsigned short* Ogb = (unsigned short*)(ws + 12 * MB);   // 4 MB [16384][128] bf16
    unsigned short* Wt  = (unsigned short*)(ws + 16 * MB);               // 96 KB
    unsigned short* WoT = (unsigned short*)(ws + 16 * MB + 112 * 1024);  // 32 KB
    float*       sumsqp = (float*)(ws + 16 * MB + 160 * 1024);           // 32 KB [8][1024]

    hipLaunchKernelGGL(k_prep, dim3(48), dim3(256), 0, stream, Wqkv, Wout, Wt, WoT, sumsqp);
    hipLaunchKernelGGL(k_qkv, dim3(256, 2), dim3(256), 0, stream, x, Wt, Qb, Kb, Vt, sumsqp);
    hipLaunchKernelGGL(k_attn, dim3(16, 32), dim3(512), 0, stream, Qb, Kb, Vt, sumsqp, Ogb);
    hipLaunchKernelGGL(k_out, dim3(256, 2), dim3(256), 0, stream, Ogb, WoT, bout, out);
}